// Round 12
// baseline (189.948 us; speedup 1.0000x reference)
//
#include <hip/hip_runtime.h>
#include <hip/hip_bf16.h>

#define SEQ 240
#define HID 4096
#define NH 16
#define HD 256

typedef float f32x4 __attribute__((ext_vector_type(4)));
typedef short s16x8 __attribute__((ext_vector_type(8)));
typedef short s16x4 __attribute__((ext_vector_type(4)));

__device__ __forceinline__ short f2bf(float f) {
    unsigned u = __builtin_bit_cast(unsigned, f);
    unsigned r = u + 0x7FFFu + ((u >> 16) & 1u);
    return (short)(r >> 16);
}

__device__ __forceinline__ s16x8 cvt8(float4 a, float4 b) {
    s16x8 r;
    r[0] = f2bf(a.x); r[1] = f2bf(a.y); r[2] = f2bf(a.z); r[3] = f2bf(a.w);
    r[4] = f2bf(b.x); r[5] = f2bf(b.y); r[6] = f2bf(b.z); r[7] = f2bf(b.w);
    return r;
}

__device__ __forceinline__ s16x8 cvtpk8(f32x4 a, f32x4 b) {
    union { unsigned u[4]; s16x8 s; } r;
    asm("v_cvt_pk_bf16_f32 %0, %1, %2" : "=v"(r.u[0]) : "v"(a[0]), "v"(a[1]));
    asm("v_cvt_pk_bf16_f32 %0, %1, %2" : "=v"(r.u[1]) : "v"(a[2]), "v"(a[3]));
    asm("v_cvt_pk_bf16_f32 %0, %1, %2" : "=v"(r.u[2]) : "v"(b[0]), "v"(b[1]));
    asm("v_cvt_pk_bf16_f32 %0, %1, %2" : "=v"(r.u[3]) : "v"(b[2]), "v"(b[3]));
    return r.s;
}

__device__ __forceinline__ void dma16(const void* g, void* l) {
    __builtin_amdgcn_global_load_lds(
        (const __attribute__((address_space(1))) unsigned int*)g,
        (__attribute__((address_space(3))) unsigned int*)l,
        16, 0, 0);
}

// ---------------------------------------------------------------------------
// Kernel 0: convert inputs f32[240][4096] -> bf16 [256][4096], rows >=240 = 0
// ---------------------------------------------------------------------------
__global__ __launch_bounds__(256) void cvt_kernel(
    const float* __restrict__ in1, const float* __restrict__ in2,
    short* __restrict__ A1, short* __restrict__ A2)
{
    const int i = blockIdx.x * 256 + threadIdx.x;
    const float* __restrict__ src = blockIdx.y ? in2 : in1;
    short* __restrict__ dst = blockIdx.y ? A2 : A1;
    const int r = i >> 9;
    const int c = (i & 511) * 8;
    s16x8 v = (s16x8){0,0,0,0,0,0,0,0};
    if (r < SEQ) {
        float4 a = *(const float4*)&src[(size_t)r * HID + c];
        float4 b = *(const float4*)&src[(size_t)r * HID + c + 4];
        v = cvt8(a, b);
    }
    *(s16x8*)&dst[(size_t)r * HID + c] = v;
}

// ---------------------------------------------------------------------------
// Kernel 1: QKV gemm — W DMA at 512B-per-row-visit contiguity (DRAM-row fix).
// W: BN=64 rows x BK=128 f32 per step; each DMA instr = 2 rows x 512B
//    contiguous; double-buffered 2x32KB LDS; counted vmcnt (never 0 in loop).
// A: NO LDS — direct global s16x8 fragment loads (bf16, L2-resident, exact
//    fragment layout), register double-buffered one step ahead, issued
//    BEFORE the W-ISSUE so in-order vmcnt retires A without draining W.
// BM=256, 4 waves m-stacked (wave tile 64x64, acc[4][4]); grid (64,3,KS);
// NIT = KC/128.  v (g==2) partials stored TRANSPOSED: pvt[z][n][m].
// ---------------------------------------------------------------------------
__global__ __launch_bounds__(256, 2) void qkv_gemm(
    const short* __restrict__ A1, const short* __restrict__ A2,
    const float* __restrict__ Wq, const float* __restrict__ Wk,
    const float* __restrict__ Wv,
    float* __restrict__ pqk, float* __restrict__ pvt, int KC)
{
    const int g  = blockIdx.y;
    const int z  = blockIdx.z;
    const int nb = blockIdx.x * 64;
    const short* __restrict__ A = (g == 0) ? A1 : A2;
    const float* __restrict__ W = (g == 0) ? Wq : (g == 1) ? Wk : Wv;

    const int tid  = threadIdx.x;
    const int lane = tid & 63;
    const int w    = tid >> 6;      // wave owns A rows w*64 .. +63
    const int lr   = lane & 15;
    const int lg   = lane >> 4;

    __shared__ float Bs[2][64 * 128];   // 2 x 32 KB (W only)

    f32x4 acc[4][4];
    #pragma unroll
    for (int m = 0; m < 4; ++m)
        #pragma unroll
        for (int n = 0; n < 4; ++n)
            acc[m][n] = (f32x4){0.f, 0.f, 0.f, 0.f};

    // W DMA: 8 instrs/wave; instr j covers row-pair p = w*8+j.
    // lane l: row = 2p + (l>>5); 16B slot s' = (l&31) ^ (row&7) (pre-swizzle).
    const float* gW[8];
    #pragma unroll
    for (int j = 0; j < 8; ++j) {
        const int p   = w * 8 + j;
        const int row = 2 * p + (lane >> 5);
        const int sl  = (lane & 31) ^ (row & 7);
        gW[j] = W + (size_t)(nb + row) * HID + (size_t)z * KC + sl * 4;
    }

    // A direct-global fragment base
    const short* __restrict__ ap = A + (size_t)(w * 64 + lr) * HID + (size_t)z * KC + lg * 8;

    // W fragment-read offsets (floats), same XOR as pre-swizzle
    int boff0[4][4], boff1[4][4];
    #pragma unroll
    for (int n = 0; n < 4; ++n)
        #pragma unroll
        for (int ks = 0; ks < 4; ++ks) {
            const int row = n * 16 + lr;
            const int sg  = ks * 8 + lg * 2;
            boff0[n][ks] = row * 128 + (((sg    ) ^ (row & 7)) << 2);
            boff1[n][ks] = row * 128 + (((sg + 1) ^ (row & 7)) << 2);
        }

#define ISSUE(bb) { _Pragma("unroll")                                        \
    for (int j = 0; j < 8; ++j) {                                            \
        dma16(gW[j], &Bs[bb][(w * 8 + j) * 256]);  gW[j] += 128; } }

#define LOAD_AF(dst, kk) { _Pragma("unroll")                                 \
    for (int m = 0; m < 4; ++m) { _Pragma("unroll")                          \
      for (int ks = 0; ks < 4; ++ks)                                         \
        dst[m*4+ks] = *(const s16x8*)(ap + (size_t)m * 16 * HID + (kk) + ks * 32); } }

    s16x8 afA[16], afB[16];

    // prologue: W(0),W(1) in flight; A(0) in regs (A after W -> A-wait leaves nothing needed)
    ISSUE(0)
    ISSUE(1)
    LOAD_AF(afA, 0)
    asm volatile("s_waitcnt vmcnt(24)" ::: "memory");   // W(0) landed (A16+W(1)8 after it)
    __builtin_amdgcn_s_barrier();
    __builtin_amdgcn_sched_barrier(0);

    const int NIT = KC / 128;
    for (int t = 0; t < NIT; ++t) {
        const int b = t & 1;
        const s16x8* af = (t & 1) ? afB : afA;

        #pragma unroll
        for (int ks = 0; ks < 4; ++ks) {
            s16x8 bf[4];
            #pragma unroll
            for (int n = 0; n < 4; ++n) {
                f32x4 x0 = *(const f32x4*)&Bs[b][boff0[n][ks]];
                f32x4 x1 = *(const f32x4*)&Bs[b][boff1[n][ks]];
                bf[n] = cvtpk8(x0, x1);
            }
            #pragma unroll
            for (int m = 0; m < 4; ++m)
                #pragma unroll
                for (int n = 0; n < 4; ++n)
                    acc[m][n] = __builtin_amdgcn_mfma_f32_16x16x32_bf16(af[m*4+ks], bf[n], acc[m][n], 0, 0, 0);
        }

        if (t + 1 < NIT) {
            // A(t+1) into the other register set, BEFORE the W issue
            if (t & 1) { LOAD_AF(afA, (t + 1) * 128) }
            else       { LOAD_AF(afB, (t + 1) * 128) }
            __builtin_amdgcn_sched_barrier(0);
            asm volatile("s_waitcnt lgkmcnt(0)" ::: "memory");
            __builtin_amdgcn_s_barrier();           // all reads of buf b sealed
            __builtin_amdgcn_sched_barrier(0);
            if (t + 2 < NIT) {
                ISSUE(b)                            // W(t+2) -> buf b
                asm volatile("s_waitcnt vmcnt(24)" ::: "memory");  // W(t+1) landed
            } else {
                asm volatile("s_waitcnt vmcnt(16)" ::: "memory");  // W(t+1) landed, A(t+1) may fly
            }
            __builtin_amdgcn_s_barrier();           // publish buf b^1
            __builtin_amdgcn_sched_barrier(0);
        }
    }
#undef ISSUE
#undef LOAD_AF

    if (g == 2) {
        float* pout = pvt + (size_t)z * HID * SEQ;
        #pragma unroll
        for (int m = 0; m < 4; ++m) {
            const int row0 = w * 64 + m * 16 + lg * 4;
            if (row0 >= SEQ) continue;
            #pragma unroll
            for (int n = 0; n < 4; ++n) {
                const int col = nb + n * 16 + lr;
                float4 o = make_float4(acc[m][n][0], acc[m][n][1], acc[m][n][2], acc[m][n][3]);
                *(float4*)&pout[(size_t)col * SEQ + row0] = o;
            }
        }
    } else {
        float* pout = pqk + (size_t)(z * 2 + g) * SEQ * HID;
        #pragma unroll
        for (int m = 0; m < 4; ++m) {
            const int row0 = w * 64 + m * 16 + lg * 4;
            if (row0 >= SEQ) continue;
            #pragma unroll
            for (int n = 0; n < 4; ++n) {
                const int col = nb + n * 16 + lr;
                #pragma unroll
                for (int r = 0; r < 4; ++r)
                    pout[(size_t)(row0 + r) * HID + col] = acc[m][n][r];
            }
        }
    }
}

// ---------------------------------------------------------------------------
// Kernel 2: reduce q/k partials + bias -> bf16 row-major
// ---------------------------------------------------------------------------
__global__ __launch_bounds__(256) void reduce_qk(
    const float* __restrict__ pqk,
    const float* __restrict__ bq, const float* __restrict__ bk,
    short* __restrict__ qb, short* __restrict__ kb, int KS)
{
    const int g   = blockIdx.y;
    const int idx = blockIdx.x * 256 + threadIdx.x;
    f32x4 s = (f32x4){0.f, 0.f, 0.f, 0.f};
    for (int z = 0; z < KS; ++z)
        s += *(const f32x4*)&pqk[(size_t)(z * 2 + g) * SEQ * HID + (size_t)idx * 4];
    const int n = (idx * 4) & (HID - 1);
    const float* bias = g ? bk : bq;
    s += *(const f32x4*)&bias[n];
    short* ob = g ? kb : qb;
    s16x4 o = (s16x4){f2bf(s[0]), f2bf(s[1]), f2bf(s[2]), f2bf(s[3])};
    *(s16x4*)&ob[(size_t)idx * 4] = o;
}

// ---------------------------------------------------------------------------
// Kernel 3: reduce transposed v partials + bias -> vtb bf16 [4096][240]
// ---------------------------------------------------------------------------
__global__ __launch_bounds__(256) void reduce_v(
    const float* __restrict__ pvt, const float* __restrict__ bv,
    short* __restrict__ vtb, int KS)
{
    const int idx = blockIdx.x * 256 + threadIdx.x;
    f32x4 s = (f32x4){0.f, 0.f, 0.f, 0.f};
    for (int z = 0; z < KS; ++z)
        s += *(const f32x4*)&pvt[(size_t)z * HID * SEQ + (size_t)idx * 4];
    const int n = idx / 60;
    const float b = bv[n];
    s16x4 o = (s16x4){f2bf(s[0] + b), f2bf(s[1] + b), f2bf(s[2] + b), f2bf(s[3] + b)};
    *(s16x4*)&vtb[(size_t)idx * 4] = o;
}

// ---------------------------------------------------------------------------
// Kernel 4: scores + softmax.  4 waves/block, jt-split, LDS cross-wave
// softmax combine.  P^T stored bf16: ptb[h][j][i].
// ---------------------------------------------------------------------------
__global__ __launch_bounds__(256) void scores_kernel(
    const short* __restrict__ qb, const short* __restrict__ kb,
    short* __restrict__ ptb)
{
    const int it   = blockIdx.x;
    const int h    = blockIdx.y;
    const int tid  = threadIdx.x;
    const int lane = tid & 63;
    const int w    = tid >> 6;
    const int lr   = lane & 15;
    const int lg   = lane >> 4;
    const int jt0  = w * 4;
    const int NJT  = (w < 3) ? 4 : 3;

    __shared__ float redmax[4][16];
    __shared__ float redsum[4][16];

    f32x4 acc[4];
    #pragma unroll
    for (int j = 0; j < 4; ++j) acc[j] = (f32x4){0.f, 0.f, 0.f, 0.f};

    const int ib = it * 16;
    const short* qrow = &qb[(size_t)(ib + lr) * HID + h * HD + lg * 8];

    for (int d0 = 0; d0 < HD; d0 += 32) {
        s16x8 afr = *(const s16x8*)&qrow[d0];
        #pragma unroll
        for (int j = 0; j < 4; ++j) {
            if (j < NJT) {
                s16x8 bfr = *(const s16x8*)&kb[(size_t)((jt0 + j) * 16 + lr) * HID + h * HD + d0 + lg * 8];
                acc[j] = __builtin_amdgcn_mfma_f32_16x16x32_bf16(afr, bfr, acc[j], 0, 0, 0);
            }
        }
    }

    const float sc = 0.0625f;
    #pragma unroll
    for (int j = 0; j < 4; ++j) acc[j] *= sc;

    #pragma unroll
    for (int r = 0; r < 4; ++r) {
        float mx = -1e30f;
        #pragma unroll
        for (int j = 0; j < 4; ++j) if (j < NJT) mx = fmaxf(mx, acc[j][r]);
        #pragma unroll
        for (int s = 1; s < 16; s <<= 1) mx = fmaxf(mx, __shfl_xor(mx, s, 64));
        if (lr == 0) redmax[w][lg * 4 + r] = mx;
    }
    __syncthreads();
    #pragma unroll
    for (int r = 0; r < 4; ++r) {
        const int i = lg * 4 + r;
        float mx = fmaxf(fmaxf(redmax[0][i], redmax[1][i]),
                         fmaxf(redmax[2][i], redmax[3][i]));
        float sum = 0.f;
        #pragma unroll
        for (int j = 0; j < 4; ++j) {
            if (j < NJT) {
                float e = expf(acc[j][r] - mx);
                acc[j][r] = e;
                sum += e;
            }
        }
        #pragma unroll
        for (int s = 1; s < 16; s <<= 1) sum += __shfl_xor(sum, s, 64);
        if (lr == 0) redsum[w][i] = sum;
    }
    __syncthreads();
    #pragma unroll
    for (int r = 0; r < 4; ++r) {
        const int i = lg * 4 + r;
        const float inv = 1.f / (redsum[0][i] + redsum[1][i] + redsum[2][i] + redsum[3][i]);
        #pragma unroll
        for (int j = 0; j < 4; ++j) if (j < NJT) acc[j][r] *= inv;
    }
    #pragma unroll
    for (int j = 0; j < 4; ++j) {
        if (j < NJT) {
            const int jj = (jt0 + j) * 16 + lr;
            s16x4 o = (s16x4){f2bf(acc[j][0]), f2bf(acc[j][1]), f2bf(acc[j][2]), f2bf(acc[j][3])};
            *(s16x4*)&ptb[(size_t)(h * SEQ + jj) * SEQ + ib + lg * 4] = o;
        }
    }
}

// ---------------------------------------------------------------------------
// Kernel 5: O = P^T V per head, 4 waves/block jt-split, all-bf16 inputs.
// ---------------------------------------------------------------------------
__global__ __launch_bounds__(256) void pv_kernel(
    const short* __restrict__ ptb, const short* __restrict__ vtb,
    float* __restrict__ out)
{
    const int dt   = blockIdx.x;
    const int h    = blockIdx.y;
    const int tid  = threadIdx.x;
    const int lane = tid & 63;
    const int w    = tid >> 6;
    const int lr   = lane & 15;
    const int lg   = lane >> 4;
    const int NJT  = (w < 3) ? 4 : 3;

    f32x4 acc[4];
    #pragma unroll
    for (int j = 0; j < 4; ++j) acc[j] = (f32x4){0.f, 0.f, 0.f, 0.f};

    const short* vrow = &vtb[(size_t)(h * HD + dt * 16 + lr) * SEQ + lg * 8];

    for (int i0 = 0; i0 < 256; i0 += 32) {
        const bool ok = (i0 + lg * 8) < SEQ;
        s16x8 bfr = (s16x8){0,0,0,0,0,0,0,0};
        if (ok) bfr = *(const s16x8*)&vrow[i0];
        #pragma unroll
        for (int j = 0; j < 4; ++j) {
            if (j < NJT) {
                const int jt = w + j * 4;
                s16x8 afr = (s16x8){0,0,0,0,0,0,0,0};
                if (ok) afr = *(const s16x8*)&ptb[(size_t)(h * SEQ + jt * 16 + lr) * SEQ + i0 + lg * 8];
                acc[j] = __builtin_amdgcn_mfma_f32_16x16x32_bf16(afr, bfr, acc[j], 0, 0, 0);
            }
        }
    }

    #pragma unroll
    for (int j = 0; j < 4; ++j) {
        if (j < NJT) {
            const int jt = w + j * 4;
            #pragma unroll
            for (int r = 0; r < 4; ++r)
                out[(size_t)(jt * 16 + lg * 4 + r) * HID + h * HD + dt * 16 + lr] = acc[j][r];
        }
    }
}

extern "C" void kernel_launch(void* const* d_in, const int* in_sizes, int n_in,
                              void* d_out, int out_size, void* d_ws, size_t ws_size,
                              hipStream_t stream) {
    const float* in1 = (const float*)d_in[0];
    const float* in2 = (const float*)d_in[1];
    const float* Wq  = (const float*)d_in[2];
    const float* bq  = (const float*)d_in[3];
    const float* Wk  = (const float*)d_in[4];
    const float* bk  = (const float*)d_in[5];
    const float* Wv  = (const float*)d_in[6];
    const float* bv  = (const float*)d_in[7];
    float* out = (float*)d_out;

    char* w = (char*)d_ws;
    short* A1  = (short*)w;  w += (size_t)256 * HID * 2;
    short* A2  = (short*)w;  w += (size_t)256 * HID * 2;
    short* qb  = (short*)w;  w += (size_t)SEQ * HID * 2;
    short* kb  = (short*)w;  w += (size_t)SEQ * HID * 2;
    short* vtb = (short*)w;  w += (size_t)HID * SEQ * 2;
    short* ptb = (short*)w;  w += (size_t)NH * SEQ * SEQ * 2;
    float* pqk = (float*)w;
    const size_t fixed  = (size_t)(w - (char*)d_ws);
    const size_t perKS  = ((size_t)2 * SEQ * HID + (size_t)HID * SEQ) * sizeof(float);

    int KS = 1;
    if (fixed + 4 * perKS <= ws_size)      KS = 4;
    else if (fixed + 2 * perKS <= ws_size) KS = 2;
    const int KC = HID / KS;
    float* pvt = pqk + (size_t)KS * 2 * SEQ * HID;

    cvt_kernel<<<dim3(512, 2), 256, 0, stream>>>(in1, in2, A1, A2);
    qkv_gemm<<<dim3(64, 3, KS), 256, 0, stream>>>(A1, A2, Wq, Wk, Wv, pqk, pvt, KC);
    reduce_qk<<<dim3(960, 2), 256, 0, stream>>>(pqk, bq, bk, qb, kb, KS);
    reduce_v<<<960, 256, 0, stream>>>(pvt, bv, vtb, KS);
    scores_kernel<<<dim3(15, 16), 256, 0, stream>>>(qb, kb, ptb);
    pv_kernel<<<dim3(16, 16), 256, 0, stream>>>(ptb, vtb, out);
}